// Round 2
// baseline (2253.327 us; speedup 1.0000x reference)
//
#include <hip/hip_runtime.h>
#include <math.h>

// Problem constants
constexpr int Bc = 32, Nc = 1024, Cc = 768, Hc = 12, HDc = 64, Mc = 128;
constexpr int NUM_STEP_C = 8;
constexpr float QSCALE = 0.35355339059327376f;      // (HD^-0.5)^0.5 = 8^-0.5
constexpr float INV_SQRT_M = 0.088388347648318447f; // 1/sqrt(128)
constexpr float EPSC = 1e-12f;

__device__ __forceinline__ float softf(float z, float thr) {
  // sign(z) * gelu_exact(|z| - thr)
  float az = fabsf(z) - thr;
  float g = 0.5f * az * (1.0f + erff(az * 0.70710678118654752f));
  return (z > 0.f) ? g : ((z < 0.f) ? -g : 0.f);
}

__device__ __forceinline__ unsigned short f2bf(float f) {
  unsigned int u = __float_as_uint(f);
  u += 0x7fffu + ((u >> 16) & 1u);  // round-to-nearest-even
  return (unsigned short)(u >> 16);
}

__device__ __forceinline__ void unpack8(uint4 raw, float* dst) {
  dst[0] = __uint_as_float(raw.x << 16);
  dst[1] = __uint_as_float(raw.x & 0xffff0000u);
  dst[2] = __uint_as_float(raw.y << 16);
  dst[3] = __uint_as_float(raw.y & 0xffff0000u);
  dst[4] = __uint_as_float(raw.z << 16);
  dst[5] = __uint_as_float(raw.z & 0xffff0000u);
  dst[6] = __uint_as_float(raw.w << 16);
  dst[7] = __uint_as_float(raw.w & 0xffff0000u);
}

// ---------------------------------------------------------------------------
// Fused QKV GEMM + qf epilogue.
// Main loop: C[i,j] = sum_k x[i,k] * qkv_w[j,k], 128x128 tile, Kstep=8, K=768.
// bj in [0,6): q columns -> scale, per-head (2 heads/tile) second GEMM against
//              rand_matrix, exp(.-||q||^2/2)/sqrt(M), store bf16 qf [B,H,N,M].
// bj in [6,12): v columns -> store f32 v [B,H,N,HD].
// ---------------------------------------------------------------------------
__global__ __launch_bounds__(256) void qkv_qf_kernel(
    const float* __restrict__ x, const float* __restrict__ w,
    const float* __restrict__ rand_m, unsigned short* __restrict__ qf16,
    float* __restrict__ vbuf) {
  __shared__ float As[8][128];
  __shared__ float Bs[8][128];
  __shared__ float qls[128][66];
  __shared__ float rnd2[64][128];
  __shared__ float hn2[128];
  const int t = threadIdx.x;
  const int bi = blockIdx.x, bj = blockIdx.y;
  const int rg = t >> 4, cg = t & 15;
  const int lrow = t >> 1, lkq = (t & 1) << 2;
  const float* Ag = x + (size_t)(bi * 128 + lrow) * Cc + lkq;
  const float* Bg = w + (size_t)(bj * 128 + lrow) * Cc + lkq;
  float acc[8][8] = {};
  for (int k0 = 0; k0 < Cc; k0 += 8) {
    float4 av = *(const float4*)(Ag + k0);
    float4 bv = *(const float4*)(Bg + k0);
    __syncthreads();
    As[lkq + 0][lrow] = av.x; As[lkq + 1][lrow] = av.y;
    As[lkq + 2][lrow] = av.z; As[lkq + 3][lrow] = av.w;
    Bs[lkq + 0][lrow] = bv.x; Bs[lkq + 1][lrow] = bv.y;
    Bs[lkq + 2][lrow] = bv.z; Bs[lkq + 3][lrow] = bv.w;
    __syncthreads();
#pragma unroll
    for (int kk = 0; kk < 8; ++kk) {
      float a[8], b[8];
      *(float4*)&a[0] = *(const float4*)&As[kk][rg * 8];
      *(float4*)&a[4] = *(const float4*)&As[kk][rg * 8 + 4];
      *(float4*)&b[0] = *(const float4*)&Bs[kk][cg * 8];
      *(float4*)&b[4] = *(const float4*)&Bs[kk][cg * 8 + 4];
#pragma unroll
      for (int i = 0; i < 8; ++i)
#pragma unroll
        for (int j = 0; j < 8; ++j)
          acc[i][j] = fmaf(a[i], b[j], acc[i][j]);
    }
  }
  const int gi0 = bi * 128;          // tile rows never straddle a batch (128|1024)
  const int b = gi0 >> 10;
  const int n0tok = gi0 & 1023;
  if (bj >= 6) {
    // ---- V epilogue ----
    const int rem = bj * 128 + cg * 8 - Cc;   // [0,768)
    const int h = rem >> 6, d0 = rem & 63;
#pragma unroll
    for (int i = 0; i < 8; ++i) {
      float* p = vbuf + (((size_t)(b * Hc + h) * Nc + n0tok + rg * 8 + i) * HDc + d0);
      *(float4*)p = *(float4*)&acc[i][0];
      *(float4*)(p + 4) = *(float4*)&acc[i][4];
    }
  } else {
    // ---- Q -> qf epilogue, two heads per tile ----
    const int ng2 = t >> 4, mg2 = t & 15;
    for (int hh = 0; hh < 2; ++hh) {
      const int h = bj * 2 + hh;
      __syncthreads();  // protect qls/rnd2 from previous iteration's readers
      if ((cg >> 3) == hh) {
        const int c0 = (cg & 7) * 8;
#pragma unroll
        for (int i = 0; i < 8; ++i)
#pragma unroll
          for (int j = 0; j < 8; ++j)
            qls[rg * 8 + i][c0 + j] = acc[i][j] * QSCALE;
      }
      const float* rgp = rand_m + (size_t)h * HDc * Mc;
#pragma unroll
      for (int c = 0; c < 8; ++c)
        ((float4*)&rnd2[0][0])[c * 256 + t] = *(const float4*)(rgp + c * 1024 + t * 4);
      __syncthreads();
      if (t < 128) {
        float s = 0.f;
#pragma unroll
        for (int d = 0; d < 64; ++d) s += qls[t][d] * qls[t][d];
        hn2[t] = 0.5f * s;
      }
      __syncthreads();
      float acc2[8][8] = {};
      for (int d = 0; d < 64; ++d) {
        float qv[8], rv[8];
#pragma unroll
        for (int i = 0; i < 8; ++i) qv[i] = qls[ng2 * 8 + i][d];
        *(float4*)&rv[0] = *(const float4*)&rnd2[d][mg2 * 8];
        *(float4*)&rv[4] = *(const float4*)&rnd2[d][mg2 * 8 + 4];
#pragma unroll
        for (int i = 0; i < 8; ++i)
#pragma unroll
          for (int j = 0; j < 8; ++j) acc2[i][j] = fmaf(qv[i], rv[j], acc2[i][j]);
      }
      unsigned short* og =
          qf16 + ((size_t)(b * Hc + h) * Nc + n0tok) * Mc;
#pragma unroll
      for (int i = 0; i < 8; ++i) {
        const int n = ng2 * 8 + i;
        const float hv = hn2[n];
        float e[8];
#pragma unroll
        for (int j = 0; j < 8; ++j)
          e[j] = expf(acc2[i][j] - hv) * INV_SQRT_M;
        uint4 w4;
        w4.x = (unsigned int)f2bf(e[0]) | ((unsigned int)f2bf(e[1]) << 16);
        w4.y = (unsigned int)f2bf(e[2]) | ((unsigned int)f2bf(e[3]) << 16);
        w4.z = (unsigned int)f2bf(e[4]) | ((unsigned int)f2bf(e[5]) << 16);
        w4.w = (unsigned int)f2bf(e[6]) | ((unsigned int)f2bf(e[7]) << 16);
        *(uint4*)(og + (size_t)n * Mc + mg2 * 8) = w4;
      }
    }
  }
}

// ---------------------------------------------------------------------------
// kk_raw[bh] = qf^T qf (128x128, K = 1024, bf16 input, f32 accum)
// ---------------------------------------------------------------------------
__global__ __launch_bounds__(256) void kk_kernel(
    const unsigned short* __restrict__ qf, float* __restrict__ kk) {
  __shared__ float qc[64][132];
  const int t = threadIdx.x, bh = blockIdx.x;
  const int rg = t >> 4, cg = t & 15;
  float acc[8][8] = {};
  const unsigned short* qg = qf + (size_t)bh * Nc * Mc;
  for (int nc = 0; nc < 16; ++nc) {
    __syncthreads();
#pragma unroll
    for (int c = 0; c < 4; ++c) {
      int lin = c * 2048 + t * 8;
      int n = lin >> 7, m = lin & 127;
      uint4 raw = *(const uint4*)(qg + (size_t)nc * 8192 + lin);
      unpack8(raw, &qc[n][m]);
    }
    __syncthreads();
    for (int n = 0; n < 64; ++n) {
      float a[8], b[8];
      *(float4*)&a[0] = *(const float4*)&qc[n][rg * 8];
      *(float4*)&a[4] = *(const float4*)&qc[n][rg * 8 + 4];
      *(float4*)&b[0] = *(const float4*)&qc[n][cg * 8];
      *(float4*)&b[4] = *(const float4*)&qc[n][cg * 8 + 4];
#pragma unroll
      for (int i = 0; i < 8; ++i)
#pragma unroll
        for (int j = 0; j < 8; ++j) acc[i][j] = fmaf(a[i], b[j], acc[i][j]);
    }
  }
  float* og = kk + (size_t)bh * Mc * Mc;
#pragma unroll
  for (int i = 0; i < 8; ++i) {
    *(float4*)(og + (size_t)(rg * 8 + i) * Mc + cg * 8) = *(float4*)&acc[i][0];
    *(float4*)(og + (size_t)(rg * 8 + i) * Mc + cg * 8 + 4) = *(float4*)&acc[i][4];
  }
}

// ---------------------------------------------------------------------------
// inp_raw[bh] = qf^T v (128x64, K = 1024)
// ---------------------------------------------------------------------------
__global__ __launch_bounds__(256) void inp_kernel(
    const unsigned short* __restrict__ qf, const float* __restrict__ v,
    float* __restrict__ inp) {
  __shared__ float qc[64][132];
  __shared__ float vc[64][68];
  const int t = threadIdx.x, bh = blockIdx.x;
  const int mg = t >> 3, dg = t & 7;
  const int m0 = mg * 4, d0 = dg * 8;
  float acc[4][8] = {};
  const unsigned short* qg = qf + (size_t)bh * Nc * Mc;
  const float* vg = v + (size_t)bh * Nc * HDc;
  for (int nc = 0; nc < 16; ++nc) {
    __syncthreads();
#pragma unroll
    for (int c = 0; c < 4; ++c) {
      int lin = c * 2048 + t * 8;
      int n = lin >> 7, m = lin & 127;
      uint4 raw = *(const uint4*)(qg + (size_t)nc * 8192 + lin);
      unpack8(raw, &qc[n][m]);
    }
#pragma unroll
    for (int c = 0; c < 4; ++c) {
      int lin = c * 1024 + t * 4;
      int n = lin >> 6, d = lin & 63;
      float4 vv = *(const float4*)(vg + (size_t)nc * 4096 + lin);
      vc[n][d] = vv.x; vc[n][d + 1] = vv.y; vc[n][d + 2] = vv.z; vc[n][d + 3] = vv.w;
    }
    __syncthreads();
    for (int n = 0; n < 64; ++n) {
      float qv[4], vv[8];
#pragma unroll
      for (int i = 0; i < 4; ++i) qv[i] = qc[n][m0 + i];
      *(float4*)&vv[0] = *(const float4*)&vc[n][d0];
      *(float4*)&vv[4] = *(const float4*)&vc[n][d0 + 4];
#pragma unroll
      for (int i = 0; i < 4; ++i)
#pragma unroll
        for (int j = 0; j < 8; ++j) acc[i][j] = fmaf(qv[i], vv[j], acc[i][j]);
    }
  }
  float* og = inp + (size_t)bh * Mc * HDc;
#pragma unroll
  for (int i = 0; i < 4; ++i) {
    *(float4*)(og + (size_t)(m0 + i) * HDc + d0) = *(float4*)&acc[i][0];
    *(float4*)(og + (size_t)(m0 + i) * HDc + d0 + 4) = *(float4*)&acc[i][4];
  }
}

// ---------------------------------------------------------------------------
// normalize in place + L
// ---------------------------------------------------------------------------
__global__ __launch_bounds__(256) void norm_kernel(float* kk, float* inp,
                                                   float* __restrict__ norms,
                                                   float* __restrict__ Lbuf) {
  __shared__ float nrm[128];
  __shared__ float rowsum[128];
  const int t = threadIdx.x, bh = blockIdx.x;
  float* kkg = kk + (size_t)bh * Mc * Mc;
  float* ig = inp + (size_t)bh * Mc * HDc;
  if (t < 128) {
    float nm = fmaxf(sqrtf(kkg[t * Mc + t]), EPSC);
    nrm[t] = nm;
    norms[(size_t)bh * Mc + t] = nm;
  }
  __syncthreads();
#pragma unroll 8
  for (int e = 0; e < 64; ++e) {
    int idx = e * 256 + t;
    int m = idx >> 7, p = idx & 127;
    kkg[idx] = kkg[idx] / (nrm[m] * nrm[p]);
  }
#pragma unroll 8
  for (int e = 0; e < 32; ++e) {
    int idx = e * 256 + t;
    int m = idx >> 6;
    ig[idx] = ig[idx] / nrm[m];
  }
  __syncthreads();
  if (t < 128) {
    float s = 0.f;
    for (int p = 0; p < 128; ++p) s += fabsf(kkg[t * Mc + p]);
    rowsum[t] = s;
  }
  __syncthreads();
  if (t == 0) {
    float mx = rowsum[0];
    for (int i = 1; i < 128; ++i) mx = fmaxf(mx, rowsum[i]);
    Lbuf[bh] = mx + 1.0f;
  }
}

// ---------------------------------------------------------------------------
// kk = learned_k @ kk @ learned_k, IN PLACE (block loads all of kk[bh] to LDS
// before any global write)
// ---------------------------------------------------------------------------
__global__ __launch_bounds__(256) void kkl_kernel(float* kk,
                                                  const float* __restrict__ lk) {
  __shared__ float Ks[128][132];
  __shared__ float Xs[128][132];
  const int t = threadIdx.x, bh = blockIdx.x;
  float* kg = kk + (size_t)bh * Mc * Mc;
#pragma unroll
  for (int c = 0; c < 16; ++c) {
    int lin = c * 1024 + t * 4;
    int r = lin >> 7, cc = lin & 127;
    float4 a = *(const float4*)(lk + lin);
    Ks[r][cc] = a.x; Ks[r][cc + 1] = a.y; Ks[r][cc + 2] = a.z; Ks[r][cc + 3] = a.w;
    float4 b = *(const float4*)(kg + lin);
    Xs[r][cc] = b.x; Xs[r][cc + 1] = b.y; Xs[r][cc + 2] = b.z; Xs[r][cc + 3] = b.w;
  }
  __syncthreads();
  const int rg = t >> 3, cgp = t & 7;
  const int r0 = rg * 4, c0 = cgp * 16;
  float tmp[4][16] = {};
  for (int p = 0; p < 128; ++p) {
    float kv[4];
#pragma unroll
    for (int i = 0; i < 4; ++i) kv[i] = Ks[r0 + i][p];
    float xv[16];
#pragma unroll
    for (int j = 0; j < 4; ++j)
      *(float4*)&xv[j * 4] = *(const float4*)&Xs[p][c0 + j * 4];
#pragma unroll
    for (int i = 0; i < 4; ++i)
#pragma unroll
      for (int j = 0; j < 16; ++j) tmp[i][j] = fmaf(kv[i], xv[j], tmp[i][j]);
  }
  __syncthreads();
#pragma unroll
  for (int i = 0; i < 4; ++i)
#pragma unroll
    for (int j = 0; j < 4; ++j)
      *(float4*)&Xs[r0 + i][c0 + j * 4] = *(float4*)&tmp[i][j * 4];
  __syncthreads();
  float acc[4][16] = {};
  for (int p = 0; p < 128; ++p) {
    float kv[4];
#pragma unroll
    for (int i = 0; i < 4; ++i) kv[i] = Xs[r0 + i][p];
    float xv[16];
#pragma unroll
    for (int j = 0; j < 4; ++j)
      *(float4*)&xv[j * 4] = *(const float4*)&Ks[p][c0 + j * 4];
#pragma unroll
    for (int i = 0; i < 4; ++i)
#pragma unroll
      for (int j = 0; j < 16; ++j) acc[i][j] = fmaf(kv[i], xv[j], acc[i][j]);
  }
#pragma unroll
  for (int i = 0; i < 4; ++i)
#pragma unroll
    for (int j = 0; j < 4; ++j)
      *(float4*)(kg + (size_t)(r0 + i) * Mc + c0 + j * 4) = *(float4*)&acc[i][j * 4];
}

// ---------------------------------------------------------------------------
// ISTA, 8 steps; writes xss = xs/norm IN PLACE over inp (per-thread same slots)
// ---------------------------------------------------------------------------
__global__ __launch_bounds__(256) void ista_kernel(
    const float* __restrict__ kkl, float* inp, const float* __restrict__ norms,
    const float* __restrict__ Lbuf, const float* __restrict__ lamp,
    const float* __restrict__ Lp) {
  __shared__ float kks[128][129];
  __shared__ float xs[128][64];
  const int t = threadIdx.x, bh = blockIdx.x;
  const float* kg = kkl + (size_t)bh * Mc * Mc;
#pragma unroll
  for (int c = 0; c < 16; ++c) {
    int lin = c * 1024 + t * 4;
    int r = lin >> 7, cc = lin & 127;
    float4 a = *(const float4*)(kg + lin);
    kks[r][cc] = a.x; kks[r][cc + 1] = a.y; kks[r][cc + 2] = a.z; kks[r][cc + 3] = a.w;
  }
  const float lam = lamp[0] * 0.1f;
  const float Ll = Lbuf[bh] / Lp[0];
  const float thr = lam / Ll;
  const float invLl = 1.0f / Ll;
  const int mg = t >> 3, dg = t & 7;
  const int m0 = mg * 4, d0 = dg * 8;
  float* ig = inp + (size_t)bh * Mc * HDc;
  float ri[4][8], xr[4][8];
#pragma unroll
  for (int i = 0; i < 4; ++i) {
    *(float4*)&ri[i][0] = *(const float4*)(ig + (size_t)(m0 + i) * HDc + d0);
    *(float4*)&ri[i][4] = *(const float4*)(ig + (size_t)(m0 + i) * HDc + d0 + 4);
  }
#pragma unroll
  for (int i = 0; i < 4; ++i)
#pragma unroll
    for (int j = 0; j < 8; ++j) xr[i][j] = softf(ri[i][j], lam);
#pragma unroll
  for (int i = 0; i < 4; ++i) {
    *(float4*)&xs[m0 + i][d0] = *(float4*)&xr[i][0];
    *(float4*)&xs[m0 + i][d0 + 4] = *(float4*)&xr[i][4];
  }
  __syncthreads();
  for (int s = 0; s < NUM_STEP_C; ++s) {
    float acc[4][8] = {};
    for (int p = 0; p < 128; ++p) {
      float kv[4];
#pragma unroll
      for (int i = 0; i < 4; ++i) kv[i] = kks[m0 + i][p];
      float xv[8];
      *(float4*)&xv[0] = *(const float4*)&xs[p][d0];
      *(float4*)&xv[4] = *(const float4*)&xs[p][d0 + 4];
#pragma unroll
      for (int i = 0; i < 4; ++i)
#pragma unroll
        for (int j = 0; j < 8; ++j) acc[i][j] = fmaf(kv[i], xv[j], acc[i][j]);
    }
#pragma unroll
    for (int i = 0; i < 4; ++i)
#pragma unroll
      for (int j = 0; j < 8; ++j)
        xr[i][j] = softf(xr[i][j] - (acc[i][j] - ri[i][j]) * invLl, thr);
    __syncthreads();
#pragma unroll
    for (int i = 0; i < 4; ++i) {
      *(float4*)&xs[m0 + i][d0] = *(float4*)&xr[i][0];
      *(float4*)&xs[m0 + i][d0 + 4] = *(float4*)&xr[i][4];
    }
    __syncthreads();
  }
#pragma unroll
  for (int i = 0; i < 4; ++i) {
    const float invn = 1.0f / norms[(size_t)bh * Mc + m0 + i];
    float4 v0, v1;
    v0.x = xr[i][0] * invn; v0.y = xr[i][1] * invn;
    v0.z = xr[i][2] * invn; v0.w = xr[i][3] * invn;
    v1.x = xr[i][4] * invn; v1.y = xr[i][5] * invn;
    v1.z = xr[i][6] * invn; v1.w = xr[i][7] * invn;
    *(float4*)(ig + (size_t)(m0 + i) * HDc + d0) = v0;
    *(float4*)(ig + (size_t)(m0 + i) * HDc + d0 + 4) = v1;
  }
}

// ---------------------------------------------------------------------------
// attn[b, n, h*64+d] = sum_m qf[b,h,n,m] * xss[b,h,m,d]  (qf bf16)
// ---------------------------------------------------------------------------
__global__ __launch_bounds__(256) void pvout_kernel(
    const unsigned short* __restrict__ qf, const float* __restrict__ xss,
    float* __restrict__ attn) {
  __shared__ float xc[128][64];
  __shared__ float qc[128][36];
  const int t = threadIdx.x;
  const int bh = blockIdx.x, nt = blockIdx.y;
  const int b = bh / Hc, h = bh % Hc;
  const float* xg = xss + (size_t)bh * Mc * HDc;
#pragma unroll
  for (int c = 0; c < 8; ++c) {
    int lin = c * 1024 + t * 4;
    int r = lin >> 6, d = lin & 63;
    *(float4*)&xc[r][d] = *(const float4*)(xg + lin);
  }
  const int ng = t >> 3, dg = t & 7;
  const int n0 = ng * 4, d0 = dg * 8;
  float acc[4][8] = {};
  const unsigned short* qg = qf + ((size_t)bh * Nc + nt * 128) * Mc;
  for (int pc = 0; pc < 4; ++pc) {
    __syncthreads();
#pragma unroll
    for (int c = 0; c < 2; ++c) {
      int lin = c * 2048 + t * 8;
      int n = lin >> 5, p = lin & 31;
      uint4 raw = *(const uint4*)(qg + (size_t)n * Mc + pc * 32 + p);
      unpack8(raw, &qc[n][p]);
    }
    __syncthreads();
    for (int p = 0; p < 32; ++p) {
      float qv[4];
#pragma unroll
      for (int i = 0; i < 4; ++i) qv[i] = qc[n0 + i][p];
      float xv[8];
      *(float4*)&xv[0] = *(const float4*)&xc[pc * 32 + p][d0];
      *(float4*)&xv[4] = *(const float4*)&xc[pc * 32 + p][d0 + 4];
#pragma unroll
      for (int i = 0; i < 4; ++i)
#pragma unroll
        for (int j = 0; j < 8; ++j) acc[i][j] = fmaf(qv[i], xv[j], acc[i][j]);
    }
  }
#pragma unroll
  for (int i = 0; i < 4; ++i) {
    float* p = attn + ((size_t)(b * Nc + nt * 128 + n0 + i)) * Cc + h * 64 + d0;
    *(float4*)p = *(float4*)&acc[i][0];
    *(float4*)(p + 4) = *(float4*)&acc[i][4];
  }
}

// ---------------------------------------------------------------------------
// proj GEMM: out[i,j] = sum_k attn[i,k] * proj_w[j,k] + bias[j]
// ---------------------------------------------------------------------------
__global__ __launch_bounds__(256) void proj_kernel(
    const float* __restrict__ A, const float* __restrict__ Bm,
    const float* __restrict__ bias, float* __restrict__ out) {
  __shared__ float As[8][128];
  __shared__ float Bs[8][128];
  const int t = threadIdx.x;
  const int bi = blockIdx.x, bj = blockIdx.y;
  const int rg = t >> 4, cg = t & 15;
  const int lrow = t >> 1, lkq = (t & 1) << 2;
  const float* Ag = A + (size_t)(bi * 128 + lrow) * Cc + lkq;
  const float* Bg = Bm + (size_t)(bj * 128 + lrow) * Cc + lkq;
  float acc[8][8] = {};
  for (int k0 = 0; k0 < Cc; k0 += 8) {
    float4 av = *(const float4*)(Ag + k0);
    float4 bv = *(const float4*)(Bg + k0);
    __syncthreads();
    As[lkq + 0][lrow] = av.x; As[lkq + 1][lrow] = av.y;
    As[lkq + 2][lrow] = av.z; As[lkq + 3][lrow] = av.w;
    Bs[lkq + 0][lrow] = bv.x; Bs[lkq + 1][lrow] = bv.y;
    Bs[lkq + 2][lrow] = bv.z; Bs[lkq + 3][lrow] = bv.w;
    __syncthreads();
#pragma unroll
    for (int kk = 0; kk < 8; ++kk) {
      float a[8], b[8];
      *(float4*)&a[0] = *(const float4*)&As[kk][rg * 8];
      *(float4*)&a[4] = *(const float4*)&As[kk][rg * 8 + 4];
      *(float4*)&b[0] = *(const float4*)&Bs[kk][cg * 8];
      *(float4*)&b[4] = *(const float4*)&Bs[kk][cg * 8 + 4];
#pragma unroll
      for (int i = 0; i < 8; ++i)
#pragma unroll
        for (int j = 0; j < 8; ++j)
          acc[i][j] = fmaf(a[i], b[j], acc[i][j]);
    }
  }
  const int gi0 = bi * 128 + rg * 8;
  const int gj0 = bj * 128 + cg * 8;
  float4 b0 = *(const float4*)(bias + gj0);
  float4 b1 = *(const float4*)(bias + gj0 + 4);
#pragma unroll
  for (int i = 0; i < 8; ++i) {
    float* p = out + (size_t)(gi0 + i) * Cc + gj0;
    float4 v0, v1;
    v0.x = acc[i][0] + b0.x; v0.y = acc[i][1] + b0.y;
    v0.z = acc[i][2] + b0.z; v0.w = acc[i][3] + b0.w;
    v1.x = acc[i][4] + b1.x; v1.y = acc[i][5] + b1.y;
    v1.z = acc[i][6] + b1.z; v1.w = acc[i][7] + b1.w;
    *(float4*)p = v0; *(float4*)(p + 4) = v1;
  }
}

// ---------------------------------------------------------------------------
extern "C" void kernel_launch(void* const* d_in, const int* in_sizes, int n_in,
                              void* d_out, int out_size, void* d_ws,
                              size_t ws_size, hipStream_t stream) {
  const float* x = (const float*)d_in[0];
  const float* qkv_w = (const float*)d_in[1];
  const float* proj_w = (const float*)d_in[2];
  const float* proj_b = (const float*)d_in[3];
  const float* rand_matrix = (const float*)d_in[4];
  const float* learned_k = (const float*)d_in[5];
  const float* learned_lam = (const float*)d_in[6];
  const float* learned_L = (const float*)d_in[7];
  float* out = (float*)d_out;

  const size_t QF = (size_t)Bc * Hc * Nc * Mc;   // 50331648 bf16 elems
  const size_t QN = (size_t)Bc * Hc * Nc * HDc;  // 25165824 f32
  const size_t KK = (size_t)Bc * Hc * Mc * Mc;   // 6291456 f32
  const size_t IN = (size_t)Bc * Hc * Mc * HDc;  // 3145728 f32
  const size_t NB = (size_t)Bc * Hc * Mc;        // 49152 f32
  const size_t need = QF * 2 + (QN + KK + IN + NB + (size_t)Bc * Hc) * 4;
  if (ws_size < need) return;  // graceful fail (absmax) instead of OOB crash

  unsigned short* qf16 = (unsigned short*)d_ws;
  float* vbuf = (float*)(qf16 + QF);   // V, later reused as attn
  float* kkbuf = vbuf + QN;            // kk, then kk_l in place
  float* inpbuf = kkbuf + KK;          // inp, then xss in place
  float* normsbuf = inpbuf + IN;
  float* Lb = normsbuf + NB;

  qkv_qf_kernel<<<dim3(256, 12), 256, 0, stream>>>(x, qkv_w, rand_matrix,
                                                   qf16, vbuf);
  kk_kernel<<<Bc * Hc, 256, 0, stream>>>(qf16, kkbuf);
  inp_kernel<<<Bc * Hc, 256, 0, stream>>>(qf16, vbuf, inpbuf);
  norm_kernel<<<Bc * Hc, 256, 0, stream>>>(kkbuf, inpbuf, normsbuf, Lb);
  kkl_kernel<<<Bc * Hc, 256, 0, stream>>>(kkbuf, learned_k);
  ista_kernel<<<Bc * Hc, 256, 0, stream>>>(kkbuf, inpbuf, normsbuf, Lb,
                                           learned_lam, learned_L);
  pvout_kernel<<<dim3(Bc * Hc, Nc / 128), 256, 0, stream>>>(qf16, inpbuf,
                                                            vbuf);
  proj_kernel<<<dim3(256, 6), 256, 0, stream>>>(vbuf, proj_w, proj_b, out);
}

// Round 3
// 757.202 us; speedup vs baseline: 2.9759x; 2.9759x over previous
//
#include <hip/hip_runtime.h>
#include <math.h>

typedef unsigned short u16;
typedef unsigned int u32;
typedef __attribute__((ext_vector_type(8))) short bf16x8;
typedef __attribute__((ext_vector_type(4))) float f32x4;

constexpr int Bc = 32, Nc = 1024, Cc = 768, Hc = 12, HDc = 64, Mc = 128;
constexpr int NUM_STEP_C = 8;
constexpr float QSCALE = 0.35355339059327376f;      // 8^-0.5
constexpr float INV_SQRT_M = 0.088388347648318447f; // 1/sqrt(128)
constexpr float EPSC = 1e-12f;

__device__ __forceinline__ float softf(float z, float thr) {
  float az = fabsf(z) - thr;
  float g = 0.5f * az * (1.0f + erff(az * 0.70710678118654752f));
  return (z > 0.f) ? g : ((z < 0.f) ? -g : 0.f);
}

__device__ __forceinline__ u16 f2bf(float f) {
  u32 u = __float_as_uint(f);
  u += 0x7fffu + ((u >> 16) & 1u);
  return (u16)(u >> 16);
}

__device__ __forceinline__ f32x4 fzero() {
  f32x4 z; z[0] = 0.f; z[1] = 0.f; z[2] = 0.f; z[3] = 0.f; return z;
}

__device__ __forceinline__ f32x4 mfma16(bf16x8 a, bf16x8 b, f32x4 c) {
  return __builtin_amdgcn_mfma_f32_16x16x32_bf16(a, b, c, 0, 0, 0);
}

// stage one 128x32 bf16 tile (row-major, ld elems) into LDS [128][40]
__device__ __forceinline__ void stage_nt(const u16* __restrict__ g, int ld,
                                         u16* lds, int t) {
#pragma unroll
  for (int c = 0; c < 2; ++c) {
    int ch = t + c * 256;
    int r = ch >> 2, kc = ch & 3;
    *(uint4*)(lds + r * 40 + kc * 8) =
        *(const uint4*)(g + (size_t)r * ld + kc * 8);
  }
}

// ---------------------------------------------------------------------------
// prep: f32 -> bf16 conversions (x, qkv_w, proj_w) + rand_matrix transpose
// ---------------------------------------------------------------------------
__global__ __launch_bounds__(256) void prep_kernel(
    const float* __restrict__ x, const float* __restrict__ qw,
    const float* __restrict__ pw, const float* __restrict__ rnd,
    u16* __restrict__ xbf, u16* __restrict__ wbf, u16* __restrict__ pwbf,
    u16* __restrict__ randt) {
  const int NX8 = 3145728, NW8 = 147456, NP8 = 73728, NR = 98304;
  const int total = NX8 + NW8 + NP8 + NR;
  for (int idx = blockIdx.x * 256 + threadIdx.x; idx < total;
       idx += gridDim.x * 256) {
    if (idx < NX8 + NW8 + NP8) {
      const float* src; u16* dst; int k;
      if (idx < NX8) { src = x; dst = xbf; k = idx; }
      else if (idx < NX8 + NW8) { src = qw; dst = wbf; k = idx - NX8; }
      else { src = pw; dst = pwbf; k = idx - NX8 - NW8; }
      float4 a = *(const float4*)(src + (size_t)k * 8);
      float4 b = *(const float4*)(src + (size_t)k * 8 + 4);
      uint4 o;
      o.x = (u32)f2bf(a.x) | ((u32)f2bf(a.y) << 16);
      o.y = (u32)f2bf(a.z) | ((u32)f2bf(a.w) << 16);
      o.z = (u32)f2bf(b.x) | ((u32)f2bf(b.y) << 16);
      o.w = (u32)f2bf(b.z) | ((u32)f2bf(b.w) << 16);
      *(uint4*)(dst + (size_t)k * 8) = o;
    } else {
      int k = idx - NX8 - NW8 - NP8;           // rand_t[h][m][d]
      int h = k >> 13, rem = k & 8191, m = rem >> 6, d = rem & 63;
      randt[k] = f2bf(rnd[(size_t)h * 8192 + d * 128 + m]);
    }
  }
}

// ---------------------------------------------------------------------------
// Fused QKV MFMA GEMM + qf epilogue.
// C[i,j] = sum_k xbf[i,k]*wbf[j,k]; bj<6: q -> qf (bf16 [B,H,N,M]);
// bj>=6: v -> vb_t (bf16 [B,H,HD,N]).
// ---------------------------------------------------------------------------
__global__ __launch_bounds__(256) void qkv_qf_kernel(
    const u16* __restrict__ xbf, const u16* __restrict__ wbf,
    const u16* __restrict__ randt, u16* __restrict__ qf,
    u16* __restrict__ vbt) {
  __shared__ u16 SH[18432];  // Als[128][40] | Bls[128][40]; reused as Qls[2][128][72]
  u16* Als = SH;
  u16* Bls = SH + 5120;
  const int t = threadIdx.x;
  const int bi = blockIdx.x, bj = blockIdx.y;
  const int w = t >> 6, lane = t & 63, ln = lane & 15, kg = lane >> 4;
  const int wr = w >> 1, wc = w & 1;
  f32x4 acc[4][4];
#pragma unroll
  for (int i = 0; i < 4; ++i)
#pragma unroll
    for (int j = 0; j < 4; ++j) acc[i][j] = fzero();
  const u16* Ag = xbf + (size_t)(bi * 128) * Cc;
  const u16* Bg = wbf + (size_t)(bj * 128) * Cc;
  for (int k0 = 0; k0 < Cc; k0 += 32) {
    stage_nt(Ag + k0, Cc, Als, t);
    stage_nt(Bg + k0, Cc, Bls, t);
    __syncthreads();
    bf16x8 af[4], bf[4];
#pragma unroll
    for (int i = 0; i < 4; ++i)
      af[i] = *(const bf16x8*)(Als + (wr * 64 + i * 16 + ln) * 40 + kg * 8);
#pragma unroll
    for (int j = 0; j < 4; ++j)
      bf[j] = *(const bf16x8*)(Bls + (wc * 64 + j * 16 + ln) * 40 + kg * 8);
#pragma unroll
    for (int i = 0; i < 4; ++i)
#pragma unroll
      for (int j = 0; j < 4; ++j) acc[i][j] = mfma16(af[i], bf[j], acc[i][j]);
    __syncthreads();
  }
  const int b = bi >> 3;
  const int ntile = (bi & 7) * 128;
  if (bj >= 6) {
    // ---- V: write transposed bf16 [B,H,64,1024] ----
    const int h = (bj - 6) * 2 + wc;
    u16* vt = vbt + ((size_t)(b * Hc + h) * 64) * 1024;
#pragma unroll
    for (int i = 0; i < 4; ++i)
#pragma unroll
      for (int j = 0; j < 4; ++j) {
        int d = j * 16 + ln;
        int n0 = ntile + wr * 64 + i * 16 + kg * 4;
        uint2 pv;
        pv.x = (u32)f2bf(acc[i][j][0]) | ((u32)f2bf(acc[i][j][1]) << 16);
        pv.y = (u32)f2bf(acc[i][j][2]) | ((u32)f2bf(acc[i][j][3]) << 16);
        *(uint2*)(vt + (size_t)d * 1024 + n0) = pv;
      }
  } else {
    // ---- Q -> qf epilogue ----
#pragma unroll
    for (int i = 0; i < 4; ++i)
#pragma unroll
      for (int j = 0; j < 4; ++j) acc[i][j] *= QSCALE;
    // hn[i][r] = 0.5*sum_d q^2 for row (wr*64+i*16+kg*4+r), head (bj*2+wc)
    float hn[4][4];
#pragma unroll
    for (int i = 0; i < 4; ++i)
#pragma unroll
      for (int r = 0; r < 4; ++r) {
        float s = acc[i][0][r] * acc[i][0][r] + acc[i][1][r] * acc[i][1][r] +
                  acc[i][2][r] * acc[i][2][r] + acc[i][3][r] * acc[i][3][r];
        s += __shfl_xor(s, 1); s += __shfl_xor(s, 2);
        s += __shfl_xor(s, 4); s += __shfl_xor(s, 8);
        hn[i][r] = 0.5f * s;
      }
    // stage q (bf16) to Qls[head][row][d] (row stride 72)
    u16* Qls = SH;
#pragma unroll
    for (int i = 0; i < 4; ++i)
#pragma unroll
      for (int j = 0; j < 4; ++j)
#pragma unroll
        for (int r = 0; r < 4; ++r)
          Qls[(size_t)(wc * 128 + wr * 64 + i * 16 + kg * 4 + r) * 72 +
              j * 16 + ln] = f2bf(acc[i][j][r]);
    __syncthreads();
    // qf GEMM: wave w -> head (w&1), rows (w>>1)*64..+64, K=64
    const int hq = bj * 2 + (w & 1);
    const int r0q = (w >> 1) * 64;
    const u16* rt = randt + (size_t)hq * Mc * HDc;  // [m][64]
    u16* qfb = qf + ((size_t)(b * Hc + hq) * Nc + ntile) * Mc;
    const u16* qsl = Qls + (size_t)(w & 1) * 128 * 72;
#pragma unroll
    for (int mh = 0; mh < 2; ++mh) {
      f32x4 a2[4][4];
#pragma unroll
      for (int i = 0; i < 4; ++i)
#pragma unroll
        for (int j = 0; j < 4; ++j) a2[i][j] = fzero();
#pragma unroll
      for (int ks = 0; ks < 2; ++ks) {
        bf16x8 af[4], bfr[4];
#pragma unroll
        for (int i = 0; i < 4; ++i)
          af[i] = *(const bf16x8*)(qsl + (size_t)(r0q + i * 16 + ln) * 72 +
                                   ks * 32 + kg * 8);
#pragma unroll
        for (int j = 0; j < 4; ++j)
          bfr[j] = *(const bf16x8*)(rt +
                                    (size_t)(mh * 64 + j * 16 + ln) * 64 +
                                    ks * 32 + kg * 8);
#pragma unroll
        for (int i = 0; i < 4; ++i)
#pragma unroll
          for (int j = 0; j < 4; ++j)
            a2[i][j] = mfma16(af[i], bfr[j], a2[i][j]);
      }
#pragma unroll
      for (int i = 0; i < 4; ++i)
#pragma unroll
        for (int j = 0; j < 4; ++j)
#pragma unroll
          for (int r = 0; r < 4; ++r) {
            int n = r0q + i * 16 + kg * 4 + r;
            float e = expf(a2[i][j][r] - hn[i][r]) * INV_SQRT_M;
            qfb[(size_t)n * Mc + mh * 64 + j * 16 + ln] = f2bf(e);
          }
    }
  }
}

// ---------------------------------------------------------------------------
// kk_inp: per bh, C[128 x 192] = qf^T . [qf | v]  (K = 1024)
// cols 0-127 -> kk (f32), cols 128-191 -> inp (f32). 384 threads, 6 waves.
// A staged with transpose from qf; V tile from vb_t (already transposed).
// ---------------------------------------------------------------------------
__global__ __launch_bounds__(384) void kk_inp_kernel(
    const u16* __restrict__ qf, const u16* __restrict__ vbt,
    float* __restrict__ kk, float* __restrict__ inp) {
  __shared__ u16 Atl[128 * 40];
  __shared__ u16 Vtl[64 * 40];
  const int t = threadIdx.x, bh = blockIdx.x;
  const int w = t >> 6, lane = t & 63, ln = lane & 15, kg = lane >> 4;
  const int wr = w / 3, wc = w % 3;
  const u16* qg = qf + (size_t)bh * Nc * Mc;
  const u16* vg = vbt + (size_t)bh * 64 * 1024;
  f32x4 acc[4][4];
#pragma unroll
  for (int i = 0; i < 4; ++i)
#pragma unroll
    for (int j = 0; j < 4; ++j) acc[i][j] = fzero();
  for (int kt = 0; kt < 32; ++kt) {
    const int n0 = kt * 32;
    if (t < 256) {
      // transpose-stage 32n x 128m of qf into Atl[m][n]
#pragma unroll
      for (int c = 0; c < 2; ++c) {
        int ch = t + c * 256;
        int n = ch >> 4, mc = ch & 15;
        uint4 v = *(const uint4*)(qg + (size_t)(n0 + n) * 128 + mc * 8);
        const u16* pv = (const u16*)&v;
#pragma unroll
        for (int e = 0; e < 8; ++e) Atl[(mc * 8 + e) * 40 + n] = pv[e];
      }
    } else {
      const int tt = t - 256;
#pragma unroll
      for (int c = 0; c < 2; ++c) {
        int ch = tt + c * 128;
        int d = ch >> 2, kc = ch & 3;
        *(uint4*)(Vtl + d * 40 + kc * 8) =
            *(const uint4*)(vg + (size_t)d * 1024 + n0 + kc * 8);
      }
    }
    __syncthreads();
    bf16x8 af[4], bf[4];
#pragma unroll
    for (int i = 0; i < 4; ++i)
      af[i] = *(const bf16x8*)(Atl + (wr * 64 + i * 16 + ln) * 40 + kg * 8);
    if (wc < 2) {
#pragma unroll
      for (int j = 0; j < 4; ++j)
        bf[j] = *(const bf16x8*)(Atl + (wc * 64 + j * 16 + ln) * 40 + kg * 8);
    } else {
#pragma unroll
      for (int j = 0; j < 4; ++j)
        bf[j] = *(const bf16x8*)(Vtl + (j * 16 + ln) * 40 + kg * 8);
    }
#pragma unroll
    for (int i = 0; i < 4; ++i)
#pragma unroll
      for (int j = 0; j < 4; ++j) acc[i][j] = mfma16(af[i], bf[j], acc[i][j]);
    __syncthreads();
  }
  if (wc < 2) {
    float* og = kk + (size_t)bh * Mc * Mc;
#pragma unroll
    for (int i = 0; i < 4; ++i)
#pragma unroll
      for (int j = 0; j < 4; ++j)
#pragma unroll
        for (int r = 0; r < 4; ++r)
          og[(size_t)(wr * 64 + i * 16 + kg * 4 + r) * Mc + wc * 64 + j * 16 +
             ln] = acc[i][j][r];
  } else {
    float* og = inp + (size_t)bh * Mc * HDc;
#pragma unroll
    for (int i = 0; i < 4; ++i)
#pragma unroll
      for (int j = 0; j < 4; ++j)
#pragma unroll
        for (int r = 0; r < 4; ++r)
          og[(size_t)(wr * 64 + i * 16 + kg * 4 + r) * HDc + j * 16 + ln] =
              acc[i][j][r];
  }
}

// ---------------------------------------------------------------------------
// normalize in place + L   (unchanged, validated round 2)
// ---------------------------------------------------------------------------
__global__ __launch_bounds__(256) void norm_kernel(float* kk, float* inp,
                                                   float* __restrict__ norms,
                                                   float* __restrict__ Lbuf) {
  __shared__ float nrm[128];
  __shared__ float rowsum[128];
  const int t = threadIdx.x, bh = blockIdx.x;
  float* kkg = kk + (size_t)bh * Mc * Mc;
  float* ig = inp + (size_t)bh * Mc * HDc;
  if (t < 128) {
    float nm = fmaxf(sqrtf(kkg[t * Mc + t]), EPSC);
    nrm[t] = nm;
    norms[(size_t)bh * Mc + t] = nm;
  }
  __syncthreads();
#pragma unroll 8
  for (int e = 0; e < 64; ++e) {
    int idx = e * 256 + t;
    int m = idx >> 7, p = idx & 127;
    kkg[idx] = kkg[idx] / (nrm[m] * nrm[p]);
  }
#pragma unroll 8
  for (int e = 0; e < 32; ++e) {
    int idx = e * 256 + t;
    int m = idx >> 6;
    ig[idx] = ig[idx] / nrm[m];
  }
  __syncthreads();
  if (t < 128) {
    float s = 0.f;
    for (int p = 0; p < 128; ++p) s += fabsf(kkg[t * Mc + p]);
    rowsum[t] = s;
  }
  __syncthreads();
  if (t == 0) {
    float mx = rowsum[0];
    for (int i = 1; i < 128; ++i) mx = fmaxf(mx, rowsum[i]);
    Lbuf[bh] = mx + 1.0f;
  }
}

// ---------------------------------------------------------------------------
// kk = learned_k @ kk @ learned_k, in place (unchanged, validated round 2)
// ---------------------------------------------------------------------------
__global__ __launch_bounds__(256) void kkl_kernel(float* kk,
                                                  const float* __restrict__ lk) {
  __shared__ float Ks[128][132];
  __shared__ float Xs[128][132];
  const int t = threadIdx.x, bh = blockIdx.x;
  float* kg = kk + (size_t)bh * Mc * Mc;
#pragma unroll
  for (int c = 0; c < 16; ++c) {
    int lin = c * 1024 + t * 4;
    int r = lin >> 7, cc = lin & 127;
    float4 a = *(const float4*)(lk + lin);
    Ks[r][cc] = a.x; Ks[r][cc + 1] = a.y; Ks[r][cc + 2] = a.z; Ks[r][cc + 3] = a.w;
    float4 b = *(const float4*)(kg + lin);
    Xs[r][cc] = b.x; Xs[r][cc + 1] = b.y; Xs[r][cc + 2] = b.z; Xs[r][cc + 3] = b.w;
  }
  __syncthreads();
  const int rg = t >> 3, cgp = t & 7;
  const int r0 = rg * 4, c0 = cgp * 16;
  float tmp[4][16] = {};
  for (int p = 0; p < 128; ++p) {
    float kv[4];
#pragma unroll
    for (int i = 0; i < 4; ++i) kv[i] = Ks[r0 + i][p];
    float xv[16];
#pragma unroll
    for (int j = 0; j < 4; ++j)
      *(float4*)&xv[j * 4] = *(const float4*)&Xs[p][c0 + j * 4];
#pragma unroll
    for (int i = 0; i < 4; ++i)
#pragma unroll
      for (int j = 0; j < 16; ++j) tmp[i][j] = fmaf(kv[i], xv[j], tmp[i][j]);
  }
  __syncthreads();
#pragma unroll
  for (int i = 0; i < 4; ++i)
#pragma unroll
    for (int j = 0; j < 4; ++j)
      *(float4*)&Xs[r0 + i][c0 + j * 4] = *(float4*)&tmp[i][j * 4];
  __syncthreads();
  float acc[4][16] = {};
  for (int p = 0; p < 128; ++p) {
    float kv[4];
#pragma unroll
    for (int i = 0; i < 4; ++i) kv[i] = Xs[r0 + i][p];
    float xv[16];
#pragma unroll
    for (int j = 0; j < 4; ++j)
      *(float4*)&xv[j * 4] = *(const float4*)&Ks[p][c0 + j * 4];
#pragma unroll
    for (int i = 0; i < 4; ++i)
#pragma unroll
      for (int j = 0; j < 16; ++j) acc[i][j] = fmaf(kv[i], xv[j], acc[i][j]);
  }
#pragma unroll
  for (int i = 0; i < 4; ++i)
#pragma unroll
    for (int j = 0; j < 4; ++j)
      *(float4*)(kg + (size_t)(r0 + i) * Mc + c0 + j * 4) = *(float4*)&acc[i][j * 4];
}

// ---------------------------------------------------------------------------
// ISTA (round-2 core); epilogue now writes xss_t bf16 [B,H,64,128]
// ---------------------------------------------------------------------------
__global__ __launch_bounds__(256) void ista_kernel(
    const float* __restrict__ kkl, const float* __restrict__ inp,
    const float* __restrict__ norms, const float* __restrict__ Lbuf,
    const float* __restrict__ lamp, const float* __restrict__ Lp,
    u16* __restrict__ xsst) {
  __shared__ float kks[128][129];
  __shared__ float xs[128][64];
  const int t = threadIdx.x, bh = blockIdx.x;
  const float* kg = kkl + (size_t)bh * Mc * Mc;
#pragma unroll
  for (int c = 0; c < 16; ++c) {
    int lin = c * 1024 + t * 4;
    int r = lin >> 7, cc = lin & 127;
    float4 a = *(const float4*)(kg + lin);
    kks[r][cc] = a.x; kks[r][cc + 1] = a.y; kks[r][cc + 2] = a.z; kks[r][cc + 3] = a.w;
  }
  const float lam = lamp[0] * 0.1f;
  const float Ll = Lbuf[bh] / Lp[0];
  const float thr = lam / Ll;
  const float invLl = 1.0f / Ll;
  const int mg = t >> 3, dg = t & 7;
  const int m0 = mg * 4, d0 = dg * 8;
  const float* ig = inp + (size_t)bh * Mc * HDc;
  float ri[4][8], xr[4][8];
#pragma unroll
  for (int i = 0; i < 4; ++i) {
    *(float4*)&ri[i][0] = *(const float4*)(ig + (size_t)(m0 + i) * HDc + d0);
    *(float4*)&ri[i][4] = *(const float4*)(ig + (size_t)(m0 + i) * HDc + d0 + 4);
  }
#pragma unroll
  for (int i = 0; i < 4; ++i)
#pragma unroll
    for (int j = 0; j < 8; ++j) xr[i][j] = softf(ri[i][j], lam);
#pragma unroll
  for (int i = 0; i < 4; ++i) {
    *(float4*)&xs[m0 + i][d0] = *(float4*)&xr[i][0];
    *(float4*)&xs[m0 + i][d0 + 4] = *(float4*)&xr[i][4];
  }
  __syncthreads();
  for (int s = 0; s < NUM_STEP_C; ++s) {
    float acc[4][8] = {};
    for (int p = 0; p < 128; ++p) {
      float kv[4];
#pragma unroll
      for (int i = 0; i < 4; ++i) kv[i] = kks[m0 + i][p];
      float xv[8];
      *(float4*)&xv[0] = *(const float4*)&xs[p][d0];
      *(float4*)&xv[4] = *(const float4*)&xs[p][d0 + 4];
#pragma unroll
      for (int i = 0; i < 4; ++i)
#pragma unroll
        for (int j = 0; j < 8; ++j) acc[i][j] = fmaf(kv[i], xv[j], acc[i][j]);
    }
#pragma unroll
    for (int i = 0; i < 4; ++i)
#pragma unroll
      for (int j = 0; j < 8; ++j)
        xr[i][j] = softf(xr[i][j] - (acc[i][j] - ri[i][j]) * invLl, thr);
    __syncthreads();
#pragma unroll
    for (int i = 0; i < 4; ++i) {
      *(float4*)&xs[m0 + i][d0] = *(float4*)&xr[i][0];
      *(float4*)&xs[m0 + i][d0 + 4] = *(float4*)&xr[i][4];
    }
    __syncthreads();
  }
  // write xss_t[d][m] bf16, xss = xs / norm[m]
  u16* og = xsst + (size_t)bh * HDc * Mc;
  float invn[4];
#pragma unroll
  for (int i = 0; i < 4; ++i)
    invn[i] = 1.0f / norms[(size_t)bh * Mc + m0 + i];
#pragma unroll
  for (int j = 0; j < 8; ++j) {
    uint2 pv;
    pv.x = (u32)f2bf(xr[0][j] * invn[0]) | ((u32)f2bf(xr[1][j] * invn[1]) << 16);
    pv.y = (u32)f2bf(xr[2][j] * invn[2]) | ((u32)f2bf(xr[3][j] * invn[3]) << 16);
    *(uint2*)(og + (size_t)(d0 + j) * Mc + m0) = pv;
  }
}

// ---------------------------------------------------------------------------
// pvout: attn_bf[b*N+n][h*64+d] = sum_m qf[bh][n][m] * xss_t[bh][d][m]
// grid (384, 8), 256 thr, 4 waves; tile 128n x 64d; K = 128 single-stage.
// ---------------------------------------------------------------------------
__global__ __launch_bounds__(256) void pvout_kernel(
    const u16* __restrict__ qf, const u16* __restrict__ xsst,
    u16* __restrict__ attn) {
  __shared__ u16 Apl[128 * 136];
  __shared__ u16 Bpl[64 * 136];
  const int t = threadIdx.x;
  const int bh = blockIdx.x, nt = blockIdx.y;
  const int b = bh / Hc, h = bh % Hc;
  const int w = t >> 6, lane = t & 63, ln = lane & 15, kg = lane >> 4;
  const u16* qg = qf + ((size_t)bh * Nc + nt * 128) * Mc;
  const u16* xg = xsst + (size_t)bh * HDc * Mc;
#pragma unroll
  for (int c = 0; c < 8; ++c) {
    int ch = t + c * 256;
    int r = ch >> 4, kc = ch & 15;
    *(uint4*)(Apl + r * 136 + kc * 8) =
        *(const uint4*)(qg + (size_t)r * 128 + kc * 8);
  }
#pragma unroll
  for (int c = 0; c < 4; ++c) {
    int ch = t + c * 256;
    int r = ch >> 4, kc = ch & 15;
    *(uint4*)(Bpl + r * 136 + kc * 8) =
        *(const uint4*)(xg + (size_t)r * 128 + kc * 8);
  }
  __syncthreads();
  f32x4 acc[2][4];
#pragma unroll
  for (int i = 0; i < 2; ++i)
#pragma unroll
    for (int j = 0; j < 4; ++j) acc[i][j] = fzero();
#pragma unroll
  for (int ks = 0; ks < 4; ++ks) {
    bf16x8 af[2], bf[4];
#pragma unroll
    for (int i = 0; i < 2; ++i)
      af[i] = *(const bf16x8*)(Apl + (w * 32 + i * 16 + ln) * 136 + ks * 32 +
                               kg * 8);
#pragma unroll
    for (int j = 0; j < 4; ++j)
      bf[j] = *(const bf16x8*)(Bpl + (j * 16 + ln) * 136 + ks * 32 + kg * 8);
#pragma unroll
    for (int i = 0; i < 2; ++i)
#pragma unroll
      for (int j = 0; j < 4; ++j) acc[i][j] = mfma16(af[i], bf[j], acc[i][j]);
  }
#pragma unroll
  for (int i = 0; i < 2; ++i)
#pragma unroll
    for (int j = 0; j < 4; ++j)
#pragma unroll
      for (int r = 0; r < 4; ++r) {
        int n = nt * 128 + w * 32 + i * 16 + kg * 4 + r;
        attn[((size_t)(b * Nc + n)) * Cc + h * 64 + j * 16 + ln] =
            f2bf(acc[i][j][r]);
      }
}

// ---------------------------------------------------------------------------
// proj: out[i][j] = sum_k attn_bf[i][k] * pwbf[j][k] + bias[j]  (f32 out)
// ---------------------------------------------------------------------------
__global__ __launch_bounds__(256) void proj_kernel(
    const u16* __restrict__ abf, const u16* __restrict__ pwbf,
    const float* __restrict__ bias, float* __restrict__ out) {
  __shared__ u16 Als[128 * 40];
  __shared__ u16 Bls[128 * 40];
  const int t = threadIdx.x;
  const int bi = blockIdx.x, bj = blockIdx.y;
  const int w = t >> 6, lane = t & 63, ln = lane & 15, kg = lane >> 4;
  const int wr = w >> 1, wc = w & 1;
  f32x4 acc[4][4];
#pragma unroll
  for (int i = 0; i < 4; ++i)
#pragma unroll
    for (int j = 0; j < 4; ++j) acc[i][j] = fzero();
  const u16* Ag = abf + (size_t)(bi * 128) * Cc;
  const u16* Bg = pwbf + (size_t)(bj * 128) * Cc;
  for (int k0 = 0; k0 < Cc; k0 += 32) {
    stage_nt(Ag + k0, Cc, Als, t);
    stage_nt(Bg + k0, Cc, Bls, t);
    __syncthreads();
    bf16x8 af[4], bf[4];
#pragma unroll
    for (int i = 0; i < 4; ++i)
      af[i] = *(const bf16x8*)(Als + (wr * 64 + i * 16 + ln) * 40 + kg * 8);
#pragma unroll
    for (int j = 0; j < 4; ++j)
      bf[j] = *(const bf16x8*)(Bls + (wc * 64 + j * 16 + ln) * 40 + kg * 8);
#pragma unroll
    for (int i = 0; i < 4; ++i)
#pragma unroll
      for (int j = 0; j < 4; ++j) acc[i][j] = mfma16(af[i], bf[j], acc[i][j]);
    __syncthreads();
  }
#pragma unroll
  for (int j = 0; j < 4; ++j) {
    const int gc = bj * 128 + wc * 64 + j * 16 + ln;
    const float bv = bias[gc];
#pragma unroll
    for (int i = 0; i < 4; ++i) {
      const int gr = bi * 128 + wr * 64 + i * 16 + kg * 4;
#pragma unroll
      for (int r = 0; r < 4; ++r)
        out[(size_t)(gr + r) * Cc + gc] = acc[i][j][r] + bv;
    }
  }
}

// ---------------------------------------------------------------------------
extern "C" void kernel_launch(void* const* d_in, const int* in_sizes, int n_in,
                              void* d_out, int out_size, void* d_ws,
                              size_t ws_size, hipStream_t stream) {
  const float* x = (const float*)d_in[0];
  const float* qkv_w = (const float*)d_in[1];
  const float* proj_w = (const float*)d_in[2];
  const float* proj_b = (const float*)d_in[3];
  const float* rand_matrix = (const float*)d_in[4];
  const float* learned_k = (const float*)d_in[5];
  const float* learned_lam = (const float*)d_in[6];
  const float* learned_L = (const float*)d_in[7];
  float* out = (float*)d_out;

  // u16 region sizes (elems)
  const size_t SX = 25165824;   // x_bf / attn_bf (aliased)
  const size_t SQF = 50331648;  // qf
  const size_t SVT = 25165824;  // vb_t
  const size_t SXT = 3145728;   // xss_t
  const size_t SW = 1179648;    // w_bf
  const size_t SPW = 589824;    // pw_bf
  const size_t SRT = 98304;     // rand_t
  const size_t U16TOT = SX + SQF + SVT + SXT + SW + SPW + SRT;
  const size_t SKK = 6291456, SIN = 3145728, SNM = 49152, SLB = 384;
  const size_t need = U16TOT * 2 + (SKK + SIN + SNM + SLB) * 4;
  if (ws_size < need) return;  // graceful fail rather than OOB crash

  u16* xbf = (u16*)d_ws;
  u16* qfb = xbf + SX;
  u16* vbt = qfb + SQF;
  u16* xsst = vbt + SVT;
  u16* wbf = xsst + SXT;
  u16* pwbf = wbf + SW;
  u16* randt = pwbf + SPW;
  float* kkf = (float*)(randt + SRT);
  float* inpf = kkf + SKK;
  float* normsf = inpf + SIN;
  float* Lb = normsf + SNM;
  u16* attnbf = xbf;  // alias: x_bf dead after qkv

  prep_kernel<<<2048, 256, 0, stream>>>(x, qkv_w, proj_w, rand_matrix, xbf,
                                        wbf, pwbf, randt);
  qkv_qf_kernel<<<dim3(256, 12), 256, 0, stream>>>(xbf, wbf, randt, qfb, vbt);
  kk_inp_kernel<<<Bc * Hc, 384, 0, stream>>>(qfb, vbt, kkf, inpf);
  norm_kernel<<<Bc * Hc, 256, 0, stream>>>(kkf, inpf, normsf, Lb);
  kkl_kernel<<<Bc * Hc, 256, 0, stream>>>(kkf, learned_k);
  ista_kernel<<<Bc * Hc, 256, 0, stream>>>(kkf, inpf, normsf, Lb, learned_lam,
                                           learned_L, xsst);
  pvout_kernel<<<dim3(Bc * Hc, Nc / 128), 256, 0, stream>>>(qfb, xsst, attnbf);
  proj_kernel<<<dim3(256, 6), 256, 0, stream>>>(attnbf, pwbf, proj_b, out);
}